// Round 1
// baseline (644.266 us; speedup 1.0000x reference)
//
#include <hip/hip_runtime.h>
#include <math.h>

#define B_SZ 256
#define N_TOKENS 196
#define DIM 384
#define NH 8
#define QKV_ST 1536      // NH*(2*32+128)
#define HID 1536
#define CTX_ST 1024      // NH*128
#define VT_ST 208        // padded token stride of V^T (13*16)

typedef short s16x8_base __attribute__((ext_vector_type(8)));
typedef s16x8_base __attribute__((may_alias)) s16x8;
typedef float f32x4_base __attribute__((ext_vector_type(4)));
typedef f32x4_base __attribute__((may_alias)) f32x4;

__device__ inline unsigned short f2b(float f) {
  union { float f; unsigned int u; } v; v.f = f;
  unsigned int r = (v.u + 0x7FFFu + ((v.u >> 16) & 1u)) >> 16;   // RNE, finite inputs
  return (unsigned short)r;
}

#define GLDS16(g, l)                                                        \
  __builtin_amdgcn_global_load_lds(                                         \
      (__attribute__((address_space(1))) void*)(g),                         \
      (__attribute__((address_space(3))) void*)(l), 16, 0, 0)

// ---------------- fp32 -> bf16 convert (vectorized, grid-stride) ----------------
__global__ __launch_bounds__(256)
void cvt_f32_bf16(const float* __restrict__ in, unsigned short* __restrict__ out, int n4) {
  int i = blockIdx.x * 256 + threadIdx.x;
  const int stride = gridDim.x * 256;
  for (; i < n4; i += stride) {
    float4 v = ((const float4*)in)[i];
    ushort4 o;
    o.x = f2b(v.x); o.y = f2b(v.y); o.z = f2b(v.z); o.w = f2b(v.w);
    ((ushort4*)out)[i] = o;
  }
}

// ---------------- bias matrix precompute: bf[h][208][208] f32 ----------------
__global__ __launch_bounds__(256)
void build_bias(const float* __restrict__ ab, const int* __restrict__ bidx,
                float* __restrict__ bf) {
  int i = blockIdx.x * 256 + threadIdx.x;
  if (i >= 8 * 208 * 208) return;
  int m = i % 208;
  int nh = i / 208;
  int n = nh % 208;
  int h = nh / 208;
  float v = -1e30f;                       // m-pad -> masked
  if (m < 196) {
    int nc = n < 196 ? n : 195;           // n-pad rows: values irrelevant (discarded)
    v = ab[h * 196 + bidx[nc * 196 + m]];
  }
  bf[i] = v;
}

// ---------------- bf16 MFMA GEMM: C[M][N] = A[M][K] @ B[N][K]^T + bias ----------------
// 128x128 tile, BK=32, 256 threads, wave-tile 64x64 (4x4 of 16x16x32).
// Staging via global_load_lds width=16 (m97 structure): LDS is linear in lane order.
template <int OUT_BF16>
__global__ __launch_bounds__(256)
void gemm_bf16_bt(const unsigned short* __restrict__ A,
                  const unsigned short* __restrict__ Bm,
                  const float* __restrict__ bias,
                  void* __restrict__ C, int M, int N, int K) {
  __shared__ unsigned short As[128][32];
  __shared__ unsigned short Bs[128][32];
  const int tid = threadIdx.x;
  const int lane = tid & 63, wave = tid >> 6;
  const int quad = lane >> 4, l15 = lane & 15;
  const int ntile = N >> 7;
  const int bx = blockIdx.x % ntile, by = blockIdx.x / ntile;
  const int row0 = by << 7, col0 = bx << 7;

  // wave w, call c in {0,1}: lds rows [w*32+c*16, +16), lane l -> row +(l>>2), elem col (l&3)*8
  const int grow = lane >> 2;
  const int gcol = (lane & 3) << 3;
  const unsigned short* Ag = A + (size_t)(row0 + (wave << 5) + grow) * K + gcol;
  const unsigned short* Bg = Bm + (size_t)(col0 + (wave << 5) + grow) * K + gcol;
  unsigned short* As0 = &As[wave << 5][0];
  unsigned short* Bs0 = &Bs[wave << 5][0];

  const int wr = (wave >> 1) << 6, wc = (wave & 1) << 6;

  f32x4 zero = {0.f, 0.f, 0.f, 0.f};
  f32x4 acc[4][4];
#pragma unroll
  for (int i = 0; i < 4; ++i)
#pragma unroll
    for (int j = 0; j < 4; ++j) acc[i][j] = zero;

  for (int k0 = 0; k0 < K; k0 += 32) {
    __syncthreads();                        // prev tile's frag reads done
    GLDS16(Ag + k0,                 As0);
    GLDS16(Ag + k0 + (size_t)16 * K, As0 + 512);
    GLDS16(Bg + k0,                 Bs0);
    GLDS16(Bg + k0 + (size_t)16 * K, Bs0 + 512);
    __syncthreads();                        // vmcnt(0) drained by barrier
    s16x8 af[4], bf[4];
#pragma unroll
    for (int i = 0; i < 4; ++i) {
      af[i] = *(const s16x8*)&As[wr + i * 16 + l15][quad * 8];
      bf[i] = *(const s16x8*)&Bs[wc + i * 16 + l15][quad * 8];
    }
#pragma unroll
    for (int i = 0; i < 4; ++i)
#pragma unroll
      for (int j = 0; j < 4; ++j)
        acc[i][j] = __builtin_amdgcn_mfma_f32_16x16x32_bf16(af[i], bf[j], acc[i][j], 0, 0, 0);
  }

#pragma unroll
  for (int j = 0; j < 4; ++j) {
    const int col = col0 + wc + j * 16 + l15;
    const float bj = bias[col];
#pragma unroll
    for (int i = 0; i < 4; ++i) {
      const int rowb = row0 + wr + i * 16 + quad * 4;
#pragma unroll
      for (int r = 0; r < 4; ++r) {
        float v = acc[i][j][r] + bj;
        if (OUT_BF16)
          ((unsigned short*)C)[(size_t)(rowb + r) * N + col] = f2b(v);
        else
          ((float*)C)[(size_t)(rowb + r) * N + col] = v;
      }
    }
  }
}

// ---------------- V -> V^T (per (b,h): [196][128] -> [128][208]) ----------------
__global__ __launch_bounds__(256)
void transpose_v(const unsigned short* __restrict__ qkv, unsigned short* __restrict__ vt) {
  __shared__ unsigned short ts[32][36];
  const int id = blockIdx.x;
  const int tile = id % 28;
  const int bh = id / 28;
  const int b = bh >> 3, h = bh & 7;
  const int nt = tile % 7, dt = tile / 7;
  const int n0 = nt * 32, d0 = dt * 32;
  const int t = threadIdx.x;
  {
    const int nl = t >> 3, dq = (t & 7) << 2;
    ushort4 v4; v4.x = 0; v4.y = 0; v4.z = 0; v4.w = 0;
    if (n0 + nl < 196)
      v4 = *(const ushort4*)(qkv + ((size_t)(b * 196 + n0 + nl) * QKV_ST + h * 192 + 64 + d0 + dq));
    ts[dq + 0][nl] = v4.x; ts[dq + 1][nl] = v4.y;
    ts[dq + 2][nl] = v4.z; ts[dq + 3][nl] = v4.w;
  }
  __syncthreads();
  {
    const int dl = t >> 3, nq = (t & 7) << 2;
    if (n0 + nq < VT_ST) {
      ushort4 o;
      o.x = ts[dl][nq + 0]; o.y = ts[dl][nq + 1];
      o.z = ts[dl][nq + 2]; o.w = ts[dl][nq + 3];
      *(ushort4*)(vt + ((size_t)(bh * 128 + d0 + dl) * VT_ST + n0 + nq)) = o;
    }
  }
}

// ---------------- MFMA attention: one block per (b,h), 64-row chunks ----------------
// S = qk^T*scale + bias (precomputed table), wave-local softmax, P (bf16) in LDS.
// PV computed TRANSPOSED: out^T[d][n] = mfma(A=V^T frag from GLOBAL, B=P frag from LDS)
// -> no V staging, no PV barriers, packed epilogue stores.
template <int NT>
__device__ __forceinline__ void attn_chunk(
    const int nc0, const unsigned short* __restrict__ qbase,
    const unsigned short* __restrict__ vgw,
    const float* __restrict__ bbase, unsigned short* __restrict__ ctxp,
    unsigned short (*__restrict__ Pm)[232], float* __restrict__ inv_s,
    const int w, const int quad, const int l15) {
  const float scale = 0.17677669529663687f;
  f32x4 zero = {0.f, 0.f, 0.f, 0.f};

  __syncthreads();                       // Pm/inv_s free (prev chunk's PV+epilogue done)
  if (w < NT) {
    const int n0 = nc0 + w * 16;
    s16x8 aq = *(const s16x8*)(qbase + (size_t)(n0 + l15) * QKV_ST + quad * 8);
    f32x4 sacc[13];
#pragma unroll
    for (int j = 0; j < 13; ++j) {
      s16x8 bk = *(const s16x8*)(qbase + (size_t)(j * 16 + l15) * QKV_ST + 32 + quad * 8);
      sacc[j] = __builtin_amdgcn_mfma_f32_16x16x32_bf16(aq, bk, zero, 0, 0, 0);
    }
    float mx[4] = {-1e30f, -1e30f, -1e30f, -1e30f};
    const float* brow = bbase + (size_t)(n0 + quad * 4) * 208 + l15;
#pragma unroll
    for (int j = 0; j < 13; ++j) {
#pragma unroll
      for (int r = 0; r < 4; ++r) {
        float s = fmaf(sacc[j][r], scale, brow[(size_t)r * 208 + j * 16]);
        if (j == 12) s = (l15 < 4) ? s : -1e30f;   // NaN-safe m-mask (garbage K rows)
        sacc[j][r] = s;
        mx[r] = fmaxf(mx[r], s);
      }
    }
#pragma unroll
    for (int o = 8; o > 0; o >>= 1)
#pragma unroll
      for (int r = 0; r < 4; ++r) mx[r] = fmaxf(mx[r], __shfl_xor(mx[r], o));
    const int prow = w * 16 + quad * 4;
    float sm[4] = {0.f, 0.f, 0.f, 0.f};
#pragma unroll
    for (int j = 0; j < 13; ++j) {
#pragma unroll
      for (int r = 0; r < 4; ++r) {
        float e = __expf(sacc[j][r] - mx[r]);
        sm[r] += e;
        Pm[prow + r][j * 16 + l15] = f2b(e);
      }
    }
#pragma unroll
    for (int o = 8; o > 0; o >>= 1)
#pragma unroll
      for (int r = 0; r < 4; ++r) sm[r] += __shfl_xor(sm[r], o);
    if (l15 == 0) {
#pragma unroll
      for (int r = 0; r < 4; ++r) inv_s[prow + r] = 1.f / sm[r];
    }
  }
  __syncthreads();                       // P + inv_s ready

  // PV (transposed): wave owns d in [w*32, w*32+32); no barriers.
  f32x4 acc0[NT], acc1[NT];
#pragma unroll
  for (int i = 0; i < NT; ++i) { acc0[i] = zero; acc1[i] = zero; }
#pragma unroll
  for (int ks = 0; ks < 7; ++ks) {
    s16x8 va0 = *(const s16x8*)(vgw + ks * 32);                 // V^T rows w*32+l15
    s16x8 va1 = *(const s16x8*)(vgw + 16 * VT_ST + ks * 32);    // V^T rows w*32+16+l15
#pragma unroll
    for (int i = 0; i < NT; ++i) {
      s16x8 pb = *(const s16x8*)&Pm[i * 16 + l15][ks * 32 + quad * 8];
      acc0[i] = __builtin_amdgcn_mfma_f32_16x16x32_bf16(va0, pb, acc0[i], 0, 0, 0);
      acc1[i] = __builtin_amdgcn_mfma_f32_16x16x32_bf16(va1, pb, acc1[i], 0, 0, 0);
    }
  }
  // epilogue: C layout col=l15 -> n, row=quad*4+r -> d  => 4 consecutive d per lane
#pragma unroll
  for (int i = 0; i < NT; ++i) {
    const int n = nc0 + i * 16 + l15;
    if (n < N_TOKENS) {
      const float is = inv_s[i * 16 + l15];
      unsigned short* cp = ctxp + (size_t)n * CTX_ST + w * 32 + quad * 4;
      ushort4 o0, o1;
      o0.x = f2b(acc0[i][0] * is); o0.y = f2b(acc0[i][1] * is);
      o0.z = f2b(acc0[i][2] * is); o0.w = f2b(acc0[i][3] * is);
      o1.x = f2b(acc1[i][0] * is); o1.y = f2b(acc1[i][1] * is);
      o1.z = f2b(acc1[i][2] * is); o1.w = f2b(acc1[i][3] * is);
      *(ushort4*)cp = o0;
      *(ushort4*)(cp + 16) = o1;
    }
  }
}

__global__ __launch_bounds__(256, 4)
void attn_mfma(const unsigned short* __restrict__ qkv,
               const unsigned short* __restrict__ vt,
               const float* __restrict__ biasf,
               unsigned short* __restrict__ ctx) {
  __shared__ unsigned short Pm[64][232];   // 64-row P chunk; cols 208..231 zero-pad
  __shared__ float inv_s[64];

  const int bh = blockIdx.x;
  const int b = bh >> 3, h = bh & 7;
  const int tid = threadIdx.x;
  const int lane = tid & 63, w = tid >> 6;
  const int quad = lane >> 4, l15 = lane & 15;

  const unsigned short* qbase = qkv + (size_t)b * N_TOKENS * QKV_ST + h * 192;
  const unsigned short* vgw = vt + ((size_t)bh * 128 + w * 32 + l15) * VT_ST + quad * 8;
  const float* bbase = biasf + (size_t)h * 208 * 208;
  unsigned short* ctxp = ctx + (size_t)b * N_TOKENS * CTX_ST + h * 128;

  if (tid < 64) {
    ushort4 z; z.x = 0; z.y = 0; z.z = 0; z.w = 0;
#pragma unroll
    for (int c = 208; c < 232; c += 4) *(ushort4*)&Pm[tid][c] = z;
  }

#pragma unroll 1
  for (int c = 0; c < 3; ++c)
    attn_chunk<4>(c * 64, qbase, vgw, bbase, ctxp, Pm, inv_s, w, quad, l15);
  attn_chunk<1>(192, qbase, vgw, bbase, ctxp, Pm, inv_s, w, quad, l15);
}

extern "C" void kernel_launch(void* const* d_in, const int* in_sizes, int n_in,
                              void* d_out, int out_size, void* d_ws, size_t ws_size,
                              hipStream_t stream) {
  const float* x     = (const float*)d_in[0];
  const float* Wqkv  = (const float*)d_in[1];
  const float* bqkv  = (const float*)d_in[2];
  const float* Wproj = (const float*)d_in[3];
  const float* bproj = (const float*)d_in[4];
  const float* ab    = (const float*)d_in[5];
  const int*   bidx  = (const int*)d_in[6];
  float* out = (float*)d_out;

  const size_t szWq = 589824, szWp = 393216, szX = (size_t)B_SZ * N_TOKENS * DIM;
  const size_t biasN = 8 * 208 * 208;                 // floats
  const size_t fixedB = biasN * 4 + (szWq + szWp + szX) * 2;
  // per-batch: vt 8*128*208 + qkv 196*1536 + ctx 196*1024 elements (bf16)
  const size_t perB = (212992ULL + 301056ULL + 200704ULL) * 2;
  int Bs = 256;
  while (Bs > 32 && fixedB + (size_t)Bs * perB > ws_size) Bs >>= 1;

  float* biasf = (float*)d_ws;
  unsigned short* Wqb  = (unsigned short*)(biasf + biasN);
  unsigned short* Wpb  = Wqb + szWq;
  unsigned short* xb   = Wpb + szWp;
  unsigned short* vtb  = xb + szX;
  unsigned short* qkvb = vtb + (size_t)Bs * 212992;
  unsigned short* ctxb = qkvb + (size_t)Bs * 301056;

  build_bias<<<dim3((unsigned)((biasN + 255) / 256)), dim3(256), 0, stream>>>(ab, bidx, biasf);
  cvt_f32_bf16<<<dim3(576), dim3(256), 0, stream>>>(Wqkv, Wqb, (int)(szWq / 4));
  cvt_f32_bf16<<<dim3(384), dim3(256), 0, stream>>>(Wproj, Wpb, (int)(szWp / 4));
  cvt_f32_bf16<<<dim3(4096), dim3(256), 0, stream>>>(x, xb, (int)(szX / 4));

  const int nslice = B_SZ / Bs;
  const int Ms = Bs * N_TOKENS;
  for (int s = 0; s < nslice; ++s) {
    const unsigned short* xs = xb + (size_t)s * Ms * DIM;
    float* outs = out + (size_t)s * Ms * DIM;
    gemm_bf16_bt<1><<<dim3((Ms / 128) * (HID / 128)), dim3(256), 0, stream>>>(
        xs, Wqb, bqkv, qkvb, Ms, HID, DIM);
    transpose_v<<<dim3(Bs * 8 * 28), dim3(256), 0, stream>>>(qkvb, vtb);
    attn_mfma<<<dim3(Bs * 8), dim3(256), 0, stream>>>(qkvb, vtb, biasf, ctxb);
    gemm_bf16_bt<0><<<dim3((Ms / 128) * (DIM / 128)), dim3(256), 0, stream>>>(
        ctxb, Wpb, bproj, outs, Ms, DIM, CTX_ST);
  }
}